// Round 13
// baseline (186.685 us; speedup 1.0000x reference)
//
#include <hip/hip_runtime.h>
#include <hip/hip_bf16.h>

// MHA: B=2, T=2048, C=1024, H=16, Dh=64. fp32 in/out, bf16 MFMA internally.
// ws layout (bf16 elems): [4M,7M): wq|wk|wv (bf16). [7M,8M): wo.
// [8M,12M): Q. [12M,16M): K. [16M,20M): Vt (quad-interleaved, from QKV
// epilogue). [20M,24M): AO.  x is read fp32 directly (no xb).

typedef __bf16 bf16;
typedef __attribute__((ext_vector_type(8))) __bf16 bf16x8;
typedef __attribute__((ext_vector_type(4))) __bf16 bf16x4;
typedef __attribute__((ext_vector_type(4))) float floatx4;
typedef __attribute__((ext_vector_type(4))) short short4v;

#define LOG2E 1.44269504088896340736f

__device__ __forceinline__ void gl2lds16(const void* g, void* l) {
  __builtin_amdgcn_global_load_lds((const __attribute__((address_space(1))) void*)g,
                                   (__attribute__((address_space(3))) void*)l, 16, 0, 0);
}

// 16x16x16 bf16 MFMA (k=16): B-operand layout (n=l15, k=l4*4+i) matches the
// 16x16 C/D layout exactly -> P stays in registers (verified R10-R12).
__device__ __forceinline__ floatx4 mfma16(bf16x4 a, bf16x4 b, floatx4 c) {
#if __has_builtin(__builtin_amdgcn_mfma_f32_16x16x16_bf16)
  return __builtin_amdgcn_mfma_f32_16x16x16_bf16(a, b, c, 0, 0, 0);
#elif __has_builtin(__builtin_amdgcn_mfma_f32_16x16x16bf16_1k)
  return __builtin_amdgcn_mfma_f32_16x16x16bf16_1k(
      __builtin_bit_cast(short4v, a), __builtin_bit_cast(short4v, b), c, 0, 0, 0);
#else
  floatx4 d = c;
  asm volatile("v_mfma_f32_16x16x16_bf16 %0, %1, %2, %0"
               : "+v"(d) : "v"(a), "v"(b));
  return d;
#endif
}

// ---------------- cast fp32 -> bf16 (weights only: wq | wk | wv | wo) -------
__global__ __launch_bounds__(256) void cast_w(
    const float* __restrict__ wq, const float* __restrict__ wk,
    const float* __restrict__ wv, const float* __restrict__ wo,
    bf16* __restrict__ dst)
{
  const size_t M1 = (size_t)1 << 20;
  size_t i4 = ((size_t)blockIdx.x * 256 + threadIdx.x) * 4;
  int seg = (int)(i4 >> 20);
  size_t off = i4 & (M1 - 1);
  const float* src = (seg == 0) ? wq : (seg == 1) ? wk : (seg == 2) ? wv : wo;
  float4 f = *(const float4*)(src + off);
  bf16x4 o = { (bf16)f.x, (bf16)f.y, (bf16)f.z, (bf16)f.w };
  *(bf16x4*)(dst + i4) = o;
}

// ---------------- GEMM: out[m][n] = sum_k A[m][k]*W[n][k] + bias[n] ---------
// BK=64, xor-swizzled 16B LDS groups, 32 MFMA/barrier.
// QKV: A = x in FP32 (staged fp32 via gl2lds, cvt->bf16 after ds_read);
//      mat0 -> Q (bf16, pre-scaled), mat1 -> K, mat2 -> Vt[bh][d][t']
//      (t' quad-interleaved: t' = (t&~31)|quad<<3|half<<2|(t&3)).
// Non-QKV: A bf16, fp32 out + bias.
template<bool F32OUT, bool QKV, int BN>
__global__ __launch_bounds__(256, 3) void gemm_bt(
    const void* __restrict__ Aany, const bf16* __restrict__ Wb,
    const float* __restrict__ bq, const float* __restrict__ bk,
    const float* __restrict__ bv, void* __restrict__ outb,
    bf16* __restrict__ vt, int M, int N, int K, float qscale)
{
  __shared__ char smemA[QKV ? 128 * 64 * 4 : 128 * 64 * 2];
  __shared__ bf16 Bs[BN * 64];
  const int tid = threadIdx.x;
  const int lane = tid & 63;
  const int wid = tid >> 6;
  const int l15 = lane & 15, l4 = lane >> 4;
  constexpr int I = (BN == 128) ? 4 : 2;
  const int wr = (BN == 128) ? (wid >> 1) : wid;
  const int wc = (BN == 128) ? (wid & 1) : 0;

  const bf16* W;
  const float* bias;
  float osc = 1.0f;
  int n0, mat = 0;
  bf16* outh;
  float* outf;
  if (QKV) {
    mat = blockIdx.x >> 3;
    n0 = (blockIdx.x & 7) << 7;
    W = Wb + ((size_t)mat << 20);
    bias = (mat == 0) ? bq : (mat == 1 ? bk : bv);
    if (mat == 0) osc = qscale;
    outh = (bf16*)outb + ((size_t)mat << 22);
    outf = nullptr;
  } else {
    n0 = blockIdx.x * BN;
    W = Wb;
    bias = bq;
    outf = (float*)outb;
    outh = nullptr;
  }
  const int m0 = blockIdx.y << 7;

  floatx4 acc[I][4] = {};

  for (int k0 = 0; k0 < K; k0 += 64) {
    if (QKV) {
      // stage A tile in FP32: 128 rows x 64 floats, 16 groups of float4/row,
      // group slot g holds source group (g&8)|((g&7)^(row&7))
      const float* Af = (const float*)Aany;
      float* Asf = (float*)smemA;
#pragma unroll
      for (int it = 0; it < 8; ++it) {
        int c = it * 256 + tid;
        int row = c >> 4, g = c & 15;
        int gs = (g & 8) | ((g & 7) ^ (row & 7));
        gl2lds16(Af + (size_t)(m0 + row) * K + k0 + gs * 4, Asf + c * 4);
      }
    } else {
      const bf16* Ah = (const bf16*)Aany;
      bf16* Ash = (bf16*)smemA;
#pragma unroll
      for (int it = 0; it < 4; ++it) {
        int c = it * 256 + tid;
        int row = c >> 3, gs = ((c & 7) ^ (row & 7)) << 3;
        gl2lds16(Ah + (size_t)(m0 + row) * K + k0 + gs, Ash + c * 8);
      }
    }
#pragma unroll
    for (int it = 0; it < BN / 32; ++it) {
      int c = it * 256 + tid;
      int row = c >> 3, gs = ((c & 7) ^ (row & 7)) << 3;
      gl2lds16(W + (size_t)(n0 + row) * K + k0 + gs, Bs + c * 8);
    }
    __syncthreads();
#pragma unroll
    for (int kk = 0; kk < 2; ++kk) {
      bf16x8 af[I], bfr[4];
#pragma unroll
      for (int i = 0; i < I; ++i) {
        int r = wr * (I * 16) + i * 16 + l15;
        if (QKV) {
          const float* Asf = (const float*)smemA;
          int m2 = kk * 8 + l4 * 2;
          int s1 = (m2 & 8) | ((m2 & 7) ^ (r & 7));
          int s2 = ((m2 + 1) & 8) | (((m2 + 1) & 7) ^ (r & 7));
          floatx4 fa = *(const floatx4*)(Asf + r * 64 + s1 * 4);
          floatx4 fb = *(const floatx4*)(Asf + r * 64 + s2 * 4);
          bf16x8 v = { (bf16)fa[0], (bf16)fa[1], (bf16)fa[2], (bf16)fa[3],
                       (bf16)fb[0], (bf16)fb[1], (bf16)fb[2], (bf16)fb[3] };
          af[i] = v;
        } else {
          const bf16* Ash = (const bf16*)smemA;
          int g = (kk * 4 + l4) ^ (r & 7);
          af[i] = *(const bf16x8*)(Ash + r * 64 + g * 8);
        }
      }
#pragma unroll
      for (int j = 0; j < 4; ++j) {
        int r = wc * 64 + j * 16 + l15;
        int g = (kk * 4 + l4) ^ (r & 7);
        bfr[j] = *(const bf16x8*)(Bs + r * 64 + g * 8);
      }
#pragma unroll
      for (int i = 0; i < I; ++i)
#pragma unroll
        for (int j = 0; j < 4; ++j)
          acc[i][j] = __builtin_amdgcn_mfma_f32_16x16x32_bf16(af[i], bfr[j], acc[i][j], 0, 0, 0);
    }
    __syncthreads();
  }

  if (QKV && mat == 2) {
    // write Vt[bh][d][t'] (quad-interleaved t'): b64 stores, t quad-aligned
#pragma unroll
    for (int j = 0; j < 4; ++j) {
      int col = n0 + wc * 64 + j * 16 + l15;
      float bv_ = bias[col];
      int h = col >> 6, d = col & 63;
#pragma unroll
      for (int i = 0; i < I; ++i) {
        int row = m0 + wr * (I * 16) + i * 16 + l4 * 4;
        int bb = row >> 11, t = row & 2047;
        int tp = (t & ~31) | (((t >> 2) & 3) << 3) | (((t >> 4) & 1) << 2);
        bf16x4 pk;
#pragma unroll
        for (int rg = 0; rg < 4; ++rg) pk[rg] = (bf16)(acc[i][j][rg] + bv_);
        *(bf16x4*)(vt + (((size_t)(bb * 16 + h)) << 17) + ((size_t)d << 11) + tp) = pk;
      }
    }
    return;
  }

#pragma unroll
  for (int j = 0; j < 4; ++j) {
    int col = n0 + wc * 64 + j * 16 + l15;
    float bv_ = bias[col];
#pragma unroll
    for (int i = 0; i < I; ++i) {
#pragma unroll
      for (int rg = 0; rg < 4; ++rg) {
        int row = m0 + wr * (I * 16) + i * 16 + l4 * 4 + rg;
        float v = (acc[i][j][rg] + bv_) * osc;
        if (F32OUT) outf[(size_t)row * N + col] = v;
        else        outh[(size_t)row * N + col] = (bf16)v;
      }
    }
  }
}

// ---------------- fused causal flash attention ----------------
// grid 512 1-D: bh = u&31 (head-local L2/XCD), p = u>>5 (0..15),
// q-tile PAIR (31-p, p) of 64-row tiles -> every block = exactly 33 K-tiles,
// uniform finish (no tail). 16 q/wave, Q register B-frags; S^T (A=K, B=Q)
// so each lane owns one q-row: per-lane softmax stats + 2 shuffles.
// PV via k=16 MFMA (B-layout == S^T C-layout) -> P STAYS IN REGISTERS.
// Vt quad-interleaved -> V reads are b128 with the K-identical bank pattern
// (0 conflicts). Double-buffered gl2lds staging across the pair, ONE barrier
// per tile. LDS 32 KB. Q pre-scaled by 1/sqrt(Dh)*log2e.
__global__ __launch_bounds__(256, 4) void attn_kernel(
    const bf16* __restrict__ Q, const bf16* __restrict__ Kg,
    const bf16* __restrict__ Vt, bf16* __restrict__ AO)
{
  constexpr int T = 2048, C = 1024;
  __shared__ bf16 Ks[2][64 * 64];   // [j][d], 16B groups xor'd by (j&7)
  __shared__ bf16 Vts[2][64 * 64];  // [d][j'], 16B groups xor'd by (d&7)

  const int tid = threadIdx.x;
  const int lane = tid & 63;
  const int w = tid >> 6;
  const int l15 = lane & 15, l4 = lane >> 4;

  const int u = blockIdx.x;
  const int bh = u & 31;
  const int p = u >> 5;                    // 0..15
  const size_t base = ((size_t)(bh >> 4) * T) * C + (bh & 15) * 64;
  const bf16* vtb = Vt + ((size_t)bh << 17);

  auto stageK = [&](int j0, int bufi) {
#pragma unroll
    for (int it = 0; it < 2; ++it) {
      int c = it * 256 + tid;
      int row = c >> 3, g = (c & 7) ^ (row & 7);
      gl2lds16(Kg + base + (size_t)(j0 + row) * C + g * 8, &Ks[bufi][c * 8]);
    }
  };
  auto stageV = [&](int j0, int bufi) {
#pragma unroll
    for (int it = 0; it < 2; ++it) {
      int c = it * 256 + tid;
      int d = c >> 3, g = (c & 7) ^ (d & 7);
      gl2lds16(vtb + ((size_t)d << 11) + j0 + g * 8, &Vts[bufi][c * 8]);
    }
  };

  const int qts[2] = { 31 - p, p };        // 64-row q-tiles, each exactly once
  int g = 0;                               // global tile counter -> buffer
  stageK(0, 0);
  stageV(0, 0);

  for (int seg = 0; seg < 2; ++seg) {
    const int qt = qts[seg];
    const int q0 = qt << 6;
    const int nkt = qt + 1;
    const int q = q0 + w * 16 + l15;       // this lane's q-row

    bf16x8 qf[2];
    {
      const bf16* qp = Q + base + (size_t)q * C + l4 * 8;
      qf[0] = *(const bf16x8*)(qp);
      qf[1] = *(const bf16x8*)(qp + 32);
    }
    floatx4 o[4] = {};                     // O^T: col q=l15, row d
    float mrow = -1e38f, lrow = 0.f;

    for (int jt = 0; jt < nkt; ++jt, ++g) {
      __syncthreads();  // staging of tile g visible; buf g^1 reads done
      const int cur = g & 1;
      if (jt + 1 < nkt) {
        stageK((jt + 1) << 6, cur ^ 1);
        stageV((jt + 1) << 6, cur ^ 1);
      } else if (seg == 0) {
        stageK(0, cur ^ 1);                // first tile of segment B
        stageV(0, cur ^ 1);
      }
      const int j0 = jt << 6;

      // ---- S^T = K Q^T : s4[tj], row j = tj*16+l4*4+rg, col q = l15
      floatx4 s4[4] = {};
#pragma unroll
      for (int kk = 0; kk < 2; ++kk) {
#pragma unroll
        for (int tj = 0; tj < 4; ++tj) {
          int r = tj * 16 + l15;
          int gg = (kk * 4 + l4) ^ (r & 7);
          bf16x8 kf = *(const bf16x8*)(&Ks[cur][r * 64 + gg * 8]);
          s4[tj] = __builtin_amdgcn_mfma_f32_16x16x32_bf16(kf, qf[kk], s4[tj], 0, 0, 0);
        }
      }

      // ---- causal mask (j > q): only the last (diagonal) tile
      if (jt == nkt - 1) {
#pragma unroll
        for (int tj = 0; tj < 4; ++tj) {
          int j = j0 + tj * 16 + l4 * 4;
#pragma unroll
          for (int rg = 0; rg < 4; ++rg)
            if (j + rg > q) s4[tj][rg] = -3e38f;
        }
      }

      // ---- online softmax: lane owns row q; in-register stats + 2 shuffles
      float mx = -3e38f;
#pragma unroll
      for (int tj = 0; tj < 4; ++tj)
#pragma unroll
        for (int rg = 0; rg < 4; ++rg)
          mx = fmaxf(mx, s4[tj][rg]);
      mx = fmaxf(mx, __shfl_xor(mx, 16, 64));
      mx = fmaxf(mx, __shfl_xor(mx, 32, 64));
      float mnew = fmaxf(mrow, mx);
      float al = __builtin_amdgcn_exp2f(mrow - mnew);
      mrow = mnew;
      float ps = 0.f;
#pragma unroll
      for (int tj = 0; tj < 4; ++tj)
#pragma unroll
        for (int rg = 0; rg < 4; ++rg) {
          float e = __builtin_amdgcn_exp2f(s4[tj][rg] - mnew);
          s4[tj][rg] = e;
          ps += e;
        }
      ps += __shfl_xor(ps, 16, 64);
      ps += __shfl_xor(ps, 32, 64);
      lrow = lrow * al + ps;

      // ---- rescale O^T by alpha (per-lane)
      if (!__all(al == 1.f)) {
#pragma unroll
        for (int td = 0; td < 4; ++td)
#pragma unroll
          for (int rg = 0; rg < 4; ++rg)
            o[td][rg] *= al;
      }

      // ---- P in registers (B-frag of k=16 MFMA == S^T C-layout)
      bf16x4 pf[4];
#pragma unroll
      for (int tj = 0; tj < 4; ++tj) {
        bf16x4 pk = { (bf16)s4[tj][0], (bf16)s4[tj][1],
                      (bf16)s4[tj][2], (bf16)s4[tj][3] };
        pf[tj] = pk;
      }

      // ---- O^T += Vt P^T : b128 V reads; lo half -> tj=2tk, hi -> 2tk+1
#pragma unroll
      for (int tk = 0; tk < 2; ++tk) {
#pragma unroll
        for (int td = 0; td < 4; ++td) {
          int r = td * 16 + l15;
          int gg = (tk * 4 + l4) ^ (r & 7);
          bf16x8 vf = *(const bf16x8*)(&Vts[cur][r * 64 + gg * 8]);
          bf16x4 lo = { vf[0], vf[1], vf[2], vf[3] };
          bf16x4 hi = { vf[4], vf[5], vf[6], vf[7] };
          o[td] = mfma16(lo, pf[tk * 2], o[td]);
          o[td] = mfma16(hi, pf[tk * 2 + 1], o[td]);
        }
      }
    }

    // ---- epilogue: O^T / l -> AO[q][d], b64 stores, all per-lane
    float inv = 1.0f / lrow;
#pragma unroll
    for (int td = 0; td < 4; ++td) {
      bf16x4 ok = { (bf16)(o[td][0] * inv), (bf16)(o[td][1] * inv),
                    (bf16)(o[td][2] * inv), (bf16)(o[td][3] * inv) };
      *(bf16x4*)(AO + base + (size_t)q * C + td * 16 + l4 * 4) = ok;
    }
  }
}

// ---------------- launch ----------------
extern "C" void kernel_launch(void* const* d_in, const int* in_sizes, int n_in,
                              void* d_out, int out_size, void* d_ws, size_t ws_size,
                              hipStream_t stream) {
  const float* x  = (const float*)d_in[0];
  const float* Wq = (const float*)d_in[1];
  const float* bq = (const float*)d_in[2];
  const float* Wk = (const float*)d_in[3];
  const float* bk = (const float*)d_in[4];
  const float* Wv = (const float*)d_in[5];
  const float* bv = (const float*)d_in[6];
  const float* Wo = (const float*)d_in[7];
  const float* bo = (const float*)d_in[8];

  bf16* ws = (bf16*)d_ws;
  const size_t M1 = (size_t)1 << 20;
  bf16* wqb = ws + 4 * M1;   // wq|wk|wv (1M each)
  bf16* wob = ws + 7 * M1;   // 1M
  bf16* Qp  = ws + 8 * M1;   // Q (4M) | K (4M)
  bf16* Vtp = ws + 16 * M1;  // Vt (4M), quad-interleaved, from QKV epilogue
  bf16* AOp = ws + 20 * M1;  // 4M

  // 1) cast weights to bf16 (x stays fp32; QKV stages it directly)
  cast_w<<<4096, 256, 0, stream>>>(Wq, Wk, Wv, Wo, wqb);
  // 2) fused QKV projection (A = x fp32; Q pre-scaled; V -> interleaved Vtp)
  gemm_bt<false, true, 128><<<dim3(24, 32), 256, 0, stream>>>(
      (const void*)x, wqb, bq, bk, bv, (void*)Qp, Vtp, 4096, 1024, 1024,
      0.125f * LOG2E);
  // 3) causal flash attention (paired 64q tiles, uniform 33 K-tiles/block)
  attn_kernel<<<512, 256, 0, stream>>>(Qp, Qp + 4 * M1, Vtp, AOp);
  // 4) output projection (fp32 out + bias)
  gemm_bt<true, false, 64><<<dim3(16, 32), 256, 0, stream>>>(
      (const void*)AOp, wob, bo, nullptr, nullptr, d_out, nullptr, 4096, 1024,
      1024, 1.0f);
}

// Round 14
// 180.395 us; speedup vs baseline: 1.0349x; 1.0349x over previous
//
#include <hip/hip_runtime.h>
#include <hip/hip_bf16.h>

// MHA: B=2, T=2048, C=1024, H=16, Dh=64. fp32 in/out, bf16 MFMA internally.
// ws layout (bf16 elems): [0,4M): xb. [4M,7M): wq|wk|wv. [7M,8M): wo.
// [8M,12M): Q. [12M,16M): K. [16M,20M): Vt (quad-interleaved, written by
// QKV gemm epilogue). [20M,24M): AO.  Total 48 MB.

typedef __bf16 bf16;
typedef __attribute__((ext_vector_type(8))) __bf16 bf16x8;
typedef __attribute__((ext_vector_type(4))) __bf16 bf16x4;
typedef __attribute__((ext_vector_type(4))) float floatx4;
typedef __attribute__((ext_vector_type(4))) short short4v;

#define LOG2E 1.44269504088896340736f

__device__ __forceinline__ void gl2lds16(const void* g, void* l) {
  __builtin_amdgcn_global_load_lds((const __attribute__((address_space(1))) void*)g,
                                   (__attribute__((address_space(3))) void*)l, 16, 0, 0);
}

// 16x16x16 bf16 MFMA (k=16): B-operand layout (n=l15, k=l4*4+i) matches the
// 16x16 C/D layout exactly -> P stays in registers (verified R10-R12).
__device__ __forceinline__ floatx4 mfma16(bf16x4 a, bf16x4 b, floatx4 c) {
#if __has_builtin(__builtin_amdgcn_mfma_f32_16x16x16_bf16)
  return __builtin_amdgcn_mfma_f32_16x16x16_bf16(a, b, c, 0, 0, 0);
#elif __has_builtin(__builtin_amdgcn_mfma_f32_16x16x16bf16_1k)
  return __builtin_amdgcn_mfma_f32_16x16x16bf16_1k(
      __builtin_bit_cast(short4v, a), __builtin_bit_cast(short4v, b), c, 0, 0, 0);
#else
  floatx4 d = c;
  asm volatile("v_mfma_f32_16x16x16_bf16 %0, %1, %2, %0"
               : "+v"(d) : "v"(a), "v"(b));
  return d;
#endif
}

// ---------------- cast fp32 -> bf16 (x | wq | wk | wv | wo) ----------------
__global__ __launch_bounds__(256) void cast_all(
    const float* __restrict__ x, const float* __restrict__ wq,
    const float* __restrict__ wk, const float* __restrict__ wv,
    const float* __restrict__ wo, bf16* __restrict__ dst)
{
  const size_t M1 = (size_t)1 << 20;
  size_t i4 = ((size_t)blockIdx.x * 256 + threadIdx.x) * 4;
  const float* src = x;
  size_t off = i4;
  if (i4 >= 4 * M1) {
    size_t r = i4 - 4 * M1;
    int seg = (int)(r >> 20);
    off = r & (M1 - 1);
    src = (seg == 0) ? wq : (seg == 1) ? wk : (seg == 2) ? wv : wo;
  }
  float4 f = *(const float4*)(src + off);
  bf16x4 o = { (bf16)f.x, (bf16)f.y, (bf16)f.z, (bf16)f.w };
  *(bf16x4*)(dst + i4) = o;
}

// ---------------- GEMM: out[m][n] = sum_k A[m][k]*W[n][k] + bias[n] ----------------
// BK=64, xor-swizzled 16B LDS groups, 32 MFMA/barrier.
// QKV: mat0 -> Q (bf16, pre-scaled), mat1 -> K, mat2 -> Vt[bh][d][t']
// with t' quad-interleaved within each 32-t block:
//   t' = (t&~31) | quad<<3 | half<<2 | (t&3)   (quad=(t>>2)&3, half=(t>>4)&1)
template<bool F32OUT, bool QKV, int BN>
__global__ __launch_bounds__(256, 3) void gemm_bt(
    const bf16* __restrict__ A, const bf16* __restrict__ Wb,
    const float* __restrict__ bq, const float* __restrict__ bk,
    const float* __restrict__ bv, void* __restrict__ outb,
    bf16* __restrict__ vt, int M, int N, int K, float qscale)
{
  __shared__ bf16 As[128 * 64];
  __shared__ bf16 Bs[BN * 64];
  const int tid = threadIdx.x;
  const int lane = tid & 63;
  const int wid = tid >> 6;
  const int l15 = lane & 15, l4 = lane >> 4;
  constexpr int I = (BN == 128) ? 4 : 2;
  const int wr = (BN == 128) ? (wid >> 1) : wid;
  const int wc = (BN == 128) ? (wid & 1) : 0;

  const bf16* W;
  const float* bias;
  float osc = 1.0f;
  int n0, mat = 0;
  bf16* outh;
  float* outf;
  if (QKV) {
    mat = blockIdx.x >> 3;
    n0 = (blockIdx.x & 7) << 7;
    W = Wb + ((size_t)mat << 20);
    bias = (mat == 0) ? bq : (mat == 1 ? bk : bv);
    if (mat == 0) osc = qscale;
    outh = (bf16*)outb + ((size_t)mat << 22);
    outf = nullptr;
  } else {
    n0 = blockIdx.x * BN;
    W = Wb;
    bias = bq;
    outf = (float*)outb;
    outh = nullptr;
  }
  const int m0 = blockIdx.y << 7;

  floatx4 acc[I][4] = {};

  for (int k0 = 0; k0 < K; k0 += 64) {
#pragma unroll
    for (int it = 0; it < 4; ++it) {
      int c = it * 256 + tid;
      int row = c >> 3, gs = ((c & 7) ^ (row & 7)) << 3;
      gl2lds16(A + (size_t)(m0 + row) * K + k0 + gs, As + c * 8);
    }
#pragma unroll
    for (int it = 0; it < BN / 32; ++it) {
      int c = it * 256 + tid;
      int row = c >> 3, gs = ((c & 7) ^ (row & 7)) << 3;
      gl2lds16(W + (size_t)(n0 + row) * K + k0 + gs, Bs + c * 8);
    }
    __syncthreads();
#pragma unroll
    for (int kk = 0; kk < 2; ++kk) {
      bf16x8 af[I], bfr[4];
#pragma unroll
      for (int i = 0; i < I; ++i) {
        int r = wr * (I * 16) + i * 16 + l15;
        int g = (kk * 4 + l4) ^ (r & 7);
        af[i] = *(const bf16x8*)(As + r * 64 + g * 8);
      }
#pragma unroll
      for (int j = 0; j < 4; ++j) {
        int r = wc * 64 + j * 16 + l15;
        int g = (kk * 4 + l4) ^ (r & 7);
        bfr[j] = *(const bf16x8*)(Bs + r * 64 + g * 8);
      }
#pragma unroll
      for (int i = 0; i < I; ++i)
#pragma unroll
        for (int j = 0; j < 4; ++j)
          acc[i][j] = __builtin_amdgcn_mfma_f32_16x16x32_bf16(af[i], bfr[j], acc[i][j], 0, 0, 0);
    }
    __syncthreads();
  }

  if (QKV && mat == 2) {
    // write Vt[bh][d][t'] (quad-interleaved t'): b64 stores, t quad-aligned
#pragma unroll
    for (int j = 0; j < 4; ++j) {
      int col = n0 + wc * 64 + j * 16 + l15;
      float bv_ = bias[col];
      int h = col >> 6, d = col & 63;
#pragma unroll
      for (int i = 0; i < I; ++i) {
        int row = m0 + wr * (I * 16) + i * 16 + l4 * 4;
        int bb = row >> 11, t = row & 2047;
        int tp = (t & ~31) | (((t >> 2) & 3) << 3) | (((t >> 4) & 1) << 2);
        bf16x4 pk;
#pragma unroll
        for (int rg = 0; rg < 4; ++rg) pk[rg] = (bf16)(acc[i][j][rg] + bv_);
        *(bf16x4*)(vt + (((size_t)(bb * 16 + h)) << 17) + ((size_t)d << 11) + tp) = pk;
      }
    }
    return;
  }

#pragma unroll
  for (int j = 0; j < 4; ++j) {
    int col = n0 + wc * 64 + j * 16 + l15;
    float bv_ = bias[col];
#pragma unroll
    for (int i = 0; i < I; ++i) {
#pragma unroll
      for (int rg = 0; rg < 4; ++rg) {
        int row = m0 + wr * (I * 16) + i * 16 + l4 * 4 + rg;
        float v = (acc[i][j][rg] + bv_) * osc;
        if (F32OUT) outf[(size_t)row * N + col] = v;
        else        outh[(size_t)row * N + col] = (bf16)v;
      }
    }
  }
}

// ---------------- fused causal flash attention ----------------
// grid 1024 1-D: bh = u&31 (head-local L2/XCD), p = u>>5 (0..31).
// qt mapping balances per-CU resident sets: blocks u, u+256, u+512, u+768
// land on one CU (XCD round-robin), and their qt values {31-p, p-8, 39-p,
// p-16} sum to 62 for every p-octant -> uniform per-CU work, no drain tail.
// 64 q-rows/block (16/wave, Q register B-frags), K/V tiles of 64 j,
// double-buffered gl2lds staging, ONE barrier per tile. S^T (A=K, B=Q):
// per-lane softmax stats + 2 shuffles. PV via k=16 MFMA (B-layout == S^T
// C-layout) -> P in registers. Vt quad-interleaved -> b128 V reads with
// K-identical bank pattern (0 conflicts). LDS 32 KB -> 4 blocks/CU.
// Q pre-scaled by 1/sqrt(Dh)*log2e.
__global__ __launch_bounds__(256, 4) void attn_kernel(
    const bf16* __restrict__ Q, const bf16* __restrict__ Kg,
    const bf16* __restrict__ Vt, bf16* __restrict__ AO)
{
  constexpr int T = 2048, C = 1024;
  __shared__ bf16 Ks[2][64 * 64];   // [j][d], 16B groups xor'd by (j&7)
  __shared__ bf16 Vts[2][64 * 64];  // [d][j'], 16B groups xor'd by (d&7)

  const int tid = threadIdx.x;
  const int lane = tid & 63;
  const int w = tid >> 6;
  const int l15 = lane & 15, l4 = lane >> 4;

  const int u = blockIdx.x;
  const int bh = u & 31;
  const int p = u >> 5;                    // 0..31
  int qt;                                  // balanced heavy-first mapping
  if (p < 8)       qt = 31 - p;
  else if (p < 16) qt = p - 8;
  else if (p < 24) qt = 39 - p;
  else             qt = p - 16;
  const int q0 = qt << 6;
  const int nkt = qt + 1;                  // 64-j tiles
  const size_t base = ((size_t)(bh >> 4) * T) * C + (bh & 15) * 64;
  const bf16* vtb = Vt + ((size_t)bh << 17);

  auto stageK = [&](int j0, int bufi) {
#pragma unroll
    for (int it = 0; it < 2; ++it) {
      int c = it * 256 + tid;
      int row = c >> 3, g = (c & 7) ^ (row & 7);
      gl2lds16(Kg + base + (size_t)(j0 + row) * C + g * 8, &Ks[bufi][c * 8]);
    }
  };
  auto stageV = [&](int j0, int bufi) {
#pragma unroll
    for (int it = 0; it < 2; ++it) {
      int c = it * 256 + tid;
      int d = c >> 3, g = (c & 7) ^ (d & 7);
      gl2lds16(vtb + ((size_t)d << 11) + j0 + g * 8, &Vts[bufi][c * 8]);
    }
  };

  const int q = q0 + w * 16 + l15;         // this lane's q-row

  // Q B-frags in registers
  bf16x8 qf[2];
  {
    const bf16* qp = Q + base + (size_t)q * C + l4 * 8;
    qf[0] = *(const bf16x8*)(qp);
    qf[1] = *(const bf16x8*)(qp + 32);
  }

  floatx4 o[4] = {};                       // O^T: col q=l15, row d=td*16+l4*4+rg
  float mrow = -1e38f, lrow = 0.f;

  stageK(0, 0);
  stageV(0, 0);

  for (int jt = 0; jt < nkt; ++jt) {
    __syncthreads();  // staging of tile jt visible; buf jt^1 reads done
    const int cur = jt & 1;
    if (jt + 1 < nkt) {
      stageK((jt + 1) << 6, cur ^ 1);
      stageV((jt + 1) << 6, cur ^ 1);
    }
    const int j0 = jt << 6;

    // ---- S^T = K Q^T : s4[tj], row j = tj*16+l4*4+rg, col q = l15
    floatx4 s4[4] = {};
#pragma unroll
    for (int kk = 0; kk < 2; ++kk) {
#pragma unroll
      for (int tj = 0; tj < 4; ++tj) {
        int r = tj * 16 + l15;
        int g = (kk * 4 + l4) ^ (r & 7);
        bf16x8 kf = *(const bf16x8*)(&Ks[cur][r * 64 + g * 8]);
        s4[tj] = __builtin_amdgcn_mfma_f32_16x16x32_bf16(kf, qf[kk], s4[tj], 0, 0, 0);
      }
    }

    // ---- causal mask (j > q): only the last (diagonal) tile
    if (jt == nkt - 1) {
#pragma unroll
      for (int tj = 0; tj < 4; ++tj) {
        int j = j0 + tj * 16 + l4 * 4;
#pragma unroll
        for (int rg = 0; rg < 4; ++rg)
          if (j + rg > q) s4[tj][rg] = -3e38f;
      }
    }

    // ---- online softmax: lane owns row q; in-register stats + 2 shuffles
    float mx = -3e38f;
#pragma unroll
    for (int tj = 0; tj < 4; ++tj)
#pragma unroll
      for (int rg = 0; rg < 4; ++rg)
        mx = fmaxf(mx, s4[tj][rg]);
    mx = fmaxf(mx, __shfl_xor(mx, 16, 64));
    mx = fmaxf(mx, __shfl_xor(mx, 32, 64));
    float mnew = fmaxf(mrow, mx);
    float al = __builtin_amdgcn_exp2f(mrow - mnew);
    mrow = mnew;
    float ps = 0.f;
#pragma unroll
    for (int tj = 0; tj < 4; ++tj)
#pragma unroll
      for (int rg = 0; rg < 4; ++rg) {
        float e = __builtin_amdgcn_exp2f(s4[tj][rg] - mnew);
        s4[tj][rg] = e;
        ps += e;
      }
    ps += __shfl_xor(ps, 16, 64);
    ps += __shfl_xor(ps, 32, 64);
    lrow = lrow * al + ps;

    // ---- rescale O^T by alpha (per-lane); skip when wave-uniformly 1
    if (!__all(al == 1.f)) {
#pragma unroll
      for (int td = 0; td < 4; ++td)
#pragma unroll
        for (int rg = 0; rg < 4; ++rg)
          o[td][rg] *= al;
    }

    // ---- P in registers (B-frag of k=16 MFMA == S^T C-layout)
    bf16x4 pf[4];
#pragma unroll
    for (int tj = 0; tj < 4; ++tj) {
      bf16x4 pk = { (bf16)s4[tj][0], (bf16)s4[tj][1],
                    (bf16)s4[tj][2], (bf16)s4[tj][3] };
      pf[tj] = pk;
    }

    // ---- O^T += Vt P^T : b128 V reads (K-identical bank pattern),
    //      low half -> tj=2tk, high half -> tj=2tk+1 (quad-interleaved Vt)
#pragma unroll
    for (int tk = 0; tk < 2; ++tk) {
#pragma unroll
      for (int td = 0; td < 4; ++td) {
        int r = td * 16 + l15;
        int g = (tk * 4 + l4) ^ (r & 7);
        bf16x8 vf = *(const bf16x8*)(&Vts[cur][r * 64 + g * 8]);
        bf16x4 lo = { vf[0], vf[1], vf[2], vf[3] };
        bf16x4 hi = { vf[4], vf[5], vf[6], vf[7] };
        o[td] = mfma16(lo, pf[tk * 2], o[td]);
        o[td] = mfma16(hi, pf[tk * 2 + 1], o[td]);
      }
    }
  }

  // ---- epilogue: O^T / l -> AO[q][d], b64 stores, all per-lane
  float inv = 1.0f / lrow;
#pragma unroll
  for (int td = 0; td < 4; ++td) {
    bf16x4 ok = { (bf16)(o[td][0] * inv), (bf16)(o[td][1] * inv),
                  (bf16)(o[td][2] * inv), (bf16)(o[td][3] * inv) };
    *(bf16x4*)(AO + base + (size_t)q * C + td * 16 + l4 * 4) = ok;
  }
}

// ---------------- launch ----------------
extern "C" void kernel_launch(void* const* d_in, const int* in_sizes, int n_in,
                              void* d_out, int out_size, void* d_ws, size_t ws_size,
                              hipStream_t stream) {
  const float* x  = (const float*)d_in[0];
  const float* Wq = (const float*)d_in[1];
  const float* bq = (const float*)d_in[2];
  const float* Wk = (const float*)d_in[3];
  const float* bk = (const float*)d_in[4];
  const float* Wv = (const float*)d_in[5];
  const float* bv = (const float*)d_in[6];
  const float* Wo = (const float*)d_in[7];
  const float* bo = (const float*)d_in[8];

  bf16* ws = (bf16*)d_ws;
  const size_t M1 = (size_t)1 << 20;
  bf16* xb  = ws;            // 4M
  bf16* wqb = ws + 4 * M1;   // wq|wk|wv (1M each)
  bf16* wob = ws + 7 * M1;   // 1M
  bf16* Qp  = ws + 8 * M1;   // Q (4M) | K (4M)
  bf16* Vtp = ws + 16 * M1;  // Vt (4M), quad-interleaved, from QKV epilogue
  bf16* AOp = ws + 20 * M1;  // 4M

  // 1) cast inputs to bf16
  cast_all<<<8192, 256, 0, stream>>>(x, Wq, Wk, Wv, Wo, ws);
  // 2) fused QKV projection (Q pre-scaled; V written interleaved to Vtp)
  gemm_bt<false, true, 128><<<dim3(24, 32), 256, 0, stream>>>(
      xb, wqb, bq, bk, bv, (void*)Qp, Vtp, 4096, 1024, 1024, 0.125f * LOG2E);
  // 3) causal flash attention (64q blocks, register-P, CU-balanced qt map)
  attn_kernel<<<1024, 256, 0, stream>>>(Qp, Qp + 4 * M1, Vtp, AOp);
  // 4) output projection (fp32 out + bias)
  gemm_bt<true, false, 64><<<dim3(16, 32), 256, 0, stream>>>(
      AOp, wob, bo, nullptr, nullptr, d_out, nullptr, 4096, 1024, 1024, 1.0f);
}